// Round 18
// baseline (79.972 us; speedup 1.0000x reference)
//
#include <hip/hip_runtime.h>

#define MAXM 16
#define NL_CAP 256
#define THETA 0.02f
#define SMEM_BYTES 65536

typedef unsigned short u16;
typedef u16 u16x8 __attribute__((ext_vector_type(8)));
typedef u16 u16x4 __attribute__((ext_vector_type(4)));
typedef __bf16 bf16x8 __attribute__((ext_vector_type(8)));
typedef float f32x4 __attribute__((ext_vector_type(4)));

// ==================== f32 -> bf16 (RNE) ====================

__device__ __forceinline__ u16 f2bf(float f) {
    unsigned u = __float_as_uint(f);
    return (u16)((u + 0x7fffu + ((u >> 16) & 1u)) >> 16);
}

__global__ __launch_bounds__(256)
void conv_k(const float* __restrict__ x, const float* __restrict__ b,
            u16* __restrict__ xb, u16* __restrict__ bb, long nx, long nb)
{
    long i = ((long)blockIdx.x * 256 + threadIdx.x) * 4;
    if (i < nx) {
        float4 v = *(const float4*)&x[i];
        u16x4 o = {f2bf(v.x), f2bf(v.y), f2bf(v.z), f2bf(v.w)};
        *(u16x4*)&xb[i] = o;
    }
    if (i < nb) {
        float4 v = *(const float4*)&b[i];
        u16x4 o = {f2bf(v.x), f2bf(v.y), f2bf(v.z), f2bf(v.w)};
        *(u16x4*)&bb[i] = o;
    }
}

// ==================== bf16 MFMA GEMM tile: quad-buffer, 2x32-K per phase ====
// R17 post-mortem: per-32K-step barrier+wait overhead (~400cyc) vs compute
// (~256cyc) is the GEMM wall. Phase = two 32-K sub-tiles: 8 gload_lds,
// vmcnt(8) counted across raw barriers, 32 MFMA per barrier-pair.

__device__ __forceinline__ void gload_lds16(const void* g, void* l) {
    __builtin_amdgcn_global_load_lds(
        (const __attribute__((address_space(1))) unsigned int*)g,
        (__attribute__((address_space(3))) unsigned int*)l, 16, 0, 0);
}

__device__ __forceinline__ void gemm_tile(u16* base, int tid, int bx, int by,
                                          const u16* __restrict__ A,
                                          const u16* __restrict__ B,
                                          float* __restrict__ C,
                                          int Ndim, int Kstride, int Klen)
{
    const int bm = by * 128, bn = bx * 128;
    const int wv = tid >> 6, ln = tid & 63;
    const int wr = (wv >> 1) * 64, wc = (wv & 1) * 64;
    const int fr = ln & 15, fk = (ln >> 4) * 8;

    const int r0 = tid >> 2, c0 = (tid & 3) * 8;
    const u16* Ap0 = A + (size_t)(bm + r0) * Kstride + c0;
    const u16* Ap1 = Ap0 + (size_t)64 * Kstride;
    const u16* Bp0 = B + (size_t)(bn + r0) * Kstride + c0;
    const u16* Bp1 = Bp0 + (size_t)64 * Kstride;

    f32x4 acc[4][4];
#pragma unroll
    for (int m = 0; m < 4; ++m)
#pragma unroll
        for (int n = 0; n < 4; ++n) acc[m][n] = (f32x4)0.f;

    // slots: s in 0..3, each 8192 u16 {A:4096 | B:4096}; phase p uses 2p,2p+1
#define STAGE_PHASE(p, kb)                                              \
    {                                                                   \
        _Pragma("unroll")                                               \
        for (int sub = 0; sub < 2; ++sub) {                             \
            u16* As = base + (size_t)(2 * (p) + sub) * 8192;            \
            u16* Bs = As + 4096;                                        \
            const int ko = (kb) + sub * 32;                             \
            gload_lds16(Ap0 + ko, As + wv * 512);                       \
            gload_lds16(Ap1 + ko, As + 2048 + wv * 512);                \
            gload_lds16(Bp0 + ko, Bs + wv * 512);                       \
            gload_lds16(Bp1 + ko, Bs + 2048 + wv * 512);                \
        }                                                               \
    }

    STAGE_PHASE(0, 0);

    int cur = 0;
    for (int kk = 0; kk < Klen; kk += 64) {
        const bool hasNext = (kk + 64 < Klen);
        if (hasNext) {
            STAGE_PHASE(cur ^ 1, kk + 64);
            asm volatile("s_waitcnt vmcnt(8)" ::: "memory");  // cur's 8 landed
        } else {
            asm volatile("s_waitcnt vmcnt(0)" ::: "memory");
        }
        __builtin_amdgcn_sched_barrier(0);
        __builtin_amdgcn_s_barrier();

#pragma unroll
        for (int sub = 0; sub < 2; ++sub) {
            const u16* As = base + (size_t)(2 * cur + sub) * 8192;
            const u16* Bs = As + 4096;
            u16x8 af[4], bf[4];
#pragma unroll
            for (int m = 0; m < 4; ++m)
                af[m] = *(const u16x8*)&As[(wr + m * 16 + fr) * 32 + fk];
#pragma unroll
            for (int n = 0; n < 4; ++n)
                bf[n] = *(const u16x8*)&Bs[(wc + n * 16 + fr) * 32 + fk];
#pragma unroll
            for (int m = 0; m < 4; ++m)
#pragma unroll
                for (int n = 0; n < 4; ++n)
                    acc[m][n] = __builtin_amdgcn_mfma_f32_16x16x32_bf16(
                        __builtin_bit_cast(bf16x8, af[m]),
                        __builtin_bit_cast(bf16x8, bf[n]), acc[m][n], 0, 0, 0);
        }

        __builtin_amdgcn_sched_barrier(0);
        __builtin_amdgcn_s_barrier();
        cur ^= 1;
    }
#undef STAGE_PHASE

    const int crow = (ln >> 4) * 4;
#pragma unroll
    for (int m = 0; m < 4; ++m)
#pragma unroll
        for (int n = 0; n < 4; ++n) {
            const size_t cbase = (size_t)(bm + wr + m * 16 + crow) * Ndim
                               + bn + wc + n * 16 + fr;
#pragma unroll
            for (int j = 0; j < 4; ++j)
                C[cbase + (size_t)j * Ndim] = acc[m][n][j];
        }
}

__global__ __launch_bounds__(256)
void bgemm_k(const u16* __restrict__ A, const u16* __restrict__ B,
             float* __restrict__ C, int Ndim, int Kdim)
{
    __shared__ __align__(16) unsigned char smem[SMEM_BYTES];
    gemm_tile((u16*)smem, threadIdx.x, blockIdx.x, blockIdx.y,
              A, B, C, Ndim, Kdim, Kdim);
}

// ==================== f32 fallback GEMM (ws too small) ====================

__global__ __launch_bounds__(256)
void g_sgemm_k(const float* __restrict__ A, const float* __restrict__ B,
               float* __restrict__ C, int Mdim, int Ndim, int Kdim)
{
    __shared__ __align__(16) float As[16][132];
    __shared__ __align__(16) float Bs[16][68];
    const int tid = threadIdx.x;
    const int tx = tid & 15, ty = tid >> 4;
    const int bn = blockIdx.x * 64, bm = blockIdx.y * 128;
    const int lrA = tid >> 1, lcA = (tid & 1) << 3;
    const int lrB = tid >> 2, lcB = (tid & 3) << 2;
    const float* Aptr = A + (size_t)(bm + lrA) * Kdim + lcA;
    const float* Bptr = B + (size_t)(bn + lrB) * Kdim + lcB;
    float4 a0 = *(const float4*)(Aptr);
    float4 a1 = *(const float4*)(Aptr + 4);
    float4 b0 = *(const float4*)(Bptr);
    float acc[8][4];
#pragma unroll
    for (int i = 0; i < 8; ++i)
#pragma unroll
        for (int j = 0; j < 4; ++j) acc[i][j] = 0.f;
    for (int kk = 0; kk < Kdim; kk += 16) {
        __syncthreads();
        As[lcA + 0][lrA] = a0.x; As[lcA + 1][lrA] = a0.y;
        As[lcA + 2][lrA] = a0.z; As[lcA + 3][lrA] = a0.w;
        As[lcA + 4][lrA] = a1.x; As[lcA + 5][lrA] = a1.y;
        As[lcA + 6][lrA] = a1.z; As[lcA + 7][lrA] = a1.w;
        Bs[lcB + 0][lrB] = b0.x; Bs[lcB + 1][lrB] = b0.y;
        Bs[lcB + 2][lrB] = b0.z; Bs[lcB + 3][lrB] = b0.w;
        __syncthreads();
        if (kk + 16 < Kdim) {
            a0 = *(const float4*)(Aptr + kk + 16);
            a1 = *(const float4*)(Aptr + kk + 20);
            b0 = *(const float4*)(Bptr + kk + 16);
        }
#pragma unroll
        for (int k = 0; k < 16; ++k) {
            const float4 av0 = *(const float4*)&As[k][ty * 8];
            const float4 av1 = *(const float4*)&As[k][ty * 8 + 4];
            const float4 bv  = *(const float4*)&Bs[k][tx * 4];
            const float avf[8] = {av0.x, av0.y, av0.z, av0.w, av1.x, av1.y, av1.z, av1.w};
            const float bvf[4] = {bv.x, bv.y, bv.z, bv.w};
#pragma unroll
            for (int i = 0; i < 8; ++i)
#pragma unroll
                for (int j = 0; j < 4; ++j) acc[i][j] += avf[i] * bvf[j];
        }
    }
#pragma unroll
    for (int i = 0; i < 8; ++i) {
        const int r = bm + ty * 8 + i;
        float4 v = {acc[i][0], acc[i][1], acc[i][2], acc[i][3]};
        *(float4*)&C[(size_t)r * Ndim + bn + tx * 4] = v;
    }
}

// ==================== spectral solve (device fn, 256 thr, H == 2048) ====================
// R17 cuts kept. New: Phase A Weyl bracket (|WSW^T| <= 2|w1||w2|+c|w2|^2,
// range ~17 vs 132) -> 3 rounds (cut2 rel 0.14%); Phase C+D merged per-wave
// (barrier-free): bisecting wave builds its eigenvector in two f32 passes
// (norm, then write), f32 subtract is Sterbenz-exact near the pole.

__device__ __forceinline__ double wsum(double x) {
#pragma unroll
    for (int m = 32; m; m >>= 1) x += __shfl_xor(x, m, 64);
    return x;
}
__device__ __forceinline__ float wsumf(float x) {
#pragma unroll
    for (int m = 32; m; m >>= 1) x += __shfl_xor(x, m, 64);
    return x;
}

__device__ __forceinline__ int inert(double s11, double s12, double s22,
                                     double dc, double cS)
{
    double b00 = cS - s11, b01 = -1.0 - s12, b11 = -s22;   // -S^{-1} - G
    double det = b00 * b11 - b01 * b01, tr = b00 + b11;
    int neg = (det > 0.0) ? ((tr < 0.0) ? 2 : 0) : 1;
    return (int)(dc + 0.5) + neg - 1;
}

__device__ __forceinline__ int lane_evalN32(float tf, double td, int n4,
    const float4* l0, const float4* l1, const float4* l2,
    const double* pc, bool poly, double cS,
    double& g11o, double& g12o, double& g22o)
{
    float s11 = 0.f, s12 = 0.f, s22 = 0.f, dc = 0.f;
#pragma unroll 4
    for (int i = 0; i < n4; ++i) {
        const float4 d4 = l0[i], x4 = l1[i], y4 = l2[i];
        const float dd[4] = {d4.x, d4.y, d4.z, d4.w};
        const float xx[4] = {x4.x, x4.y, x4.z, x4.w};
        const float yy[4] = {y4.x, y4.y, y4.z, y4.w};
#pragma unroll
        for (int e = 0; e < 4; ++e) {
            float den = dd[e] - tf;
            float mag = fmaxf(fabsf(den), 1e-30f);
            den = (den < 0.f) ? -mag : mag;
            const float inv = __builtin_amdgcn_rcpf(den);
            s11 = fmaf(xx[e] * xx[e], inv, s11);
            s12 = fmaf(xx[e] * yy[e], inv, s12);
            s22 = fmaf(yy[e] * yy[e], inv, s22);
            if (dd[e] < tf) dc += 1.f;
        }
    }
    double S11 = (double)s11, S12 = (double)s12, S22 = (double)s22;
    if (poly) {
        S11 += pc[0] + td * (pc[3] + td * (pc[6] + td * pc[9]));
        S12 += pc[1] + td * (pc[4] + td * (pc[7] + td * pc[10]));
        S22 += pc[2] + td * (pc[5] + td * (pc[8] + td * pc[11]));
    }
    g11o = S11; g12o = S12; g22o = S22;
    return inert(S11, S12, S22, (double)dc, cS);
}

__device__ void spec256(unsigned char* smem, int tid,
                        const float* __restrict__ av, const float* __restrict__ pv,
                        const float* __restrict__ qv, double* __restrict__ hdr,
                        float* __restrict__ V)
{
    __builtin_amdgcn_s_setprio(1);

    float* sd2 = (float*)smem;          // 2048
    float* sw1 = sd2 + 2048;
    float* sw2 = sw1 + 2048;
    float* nl0 = sw2 + 2048;            // NL_CAP each
    float* nl1 = nl0 + NL_CAP;
    float* nl2 = nl1 + NL_CAP;
    double* dsh = (double*)(nl2 + NL_CAP);   // 192 doubles
    int* ish = (int*)(dsh + 192);            // 16 ints

    const int lane = tid & 63, wv = tid >> 6;
    const int j0 = tid * 8;

    float d2r[8], w1r[8], w2r[8];
    double cS = 0, n1 = 0, n2 = 0, mx = 0;
#pragma unroll
    for (int h = 0; h < 2; ++h) {
        float4 aa = *(const float4*)&av[j0 + h * 4];
        float4 pp = *(const float4*)&pv[j0 + h * 4];
        float4 qq = *(const float4*)&qv[j0 + h * 4];
        const float a4[4] = {aa.x, aa.y, aa.z, aa.w};
        const float p4[4] = {pp.x, pp.y, pp.z, pp.w};
        const float q4[4] = {qq.x, qq.y, qq.z, qq.w};
#pragma unroll
        for (int e = 0; e < 4; ++e) {
            const int ix = h * 4 + e;
            d2r[ix] = a4[e] * a4[e];
            w1r[ix] = a4[e] * p4[e];
            w2r[ix] = q4[e];
            sd2[j0 + ix] = d2r[ix]; sw1[j0 + ix] = w1r[ix]; sw2[j0 + ix] = w2r[ix];
            cS += (double)p4[e] * p4[e];
            n1 += (double)w1r[ix] * w1r[ix];
            n2 += (double)w2r[ix] * w2r[ix];
            mx = fmax(mx, (double)d2r[ix]);
        }
    }
    cS = wsum(cS); n1 = wsum(n1); n2 = wsum(n2);
#pragma unroll
    for (int m_ = 32; m_; m_ >>= 1) mx = fmax(mx, __shfl_xor(mx, m_, 64));
    __syncthreads();
    if (lane == 0) { dsh[wv] = cS; dsh[4 + wv] = n1; dsh[8 + wv] = n2; dsh[12 + wv] = mx; }
    __syncthreads();
    cS = 0; n1 = 0; n2 = 0; mx = 0;
    for (int w = 0; w < 4; ++w) {
        cS += dsh[w]; n1 += dsh[4 + w]; n2 += dsh[8 + w];
        mx = fmax(mx, dsh[12 + w]);
    }
    __syncthreads();

    // ---- Phase A: lambda_max 5-section x 3 rounds on Weyl bracket ----
    // ||WSW^T|| <= 2|w1||w2| + c|w2|^2  =>  lmax in [mx-pert, mx+pert].
    const double pert = 2.0 * sqrt(n1 * n2) + cS * n2;
    double lo = fmax(0.0, mx - pert);
    double hi = mx + pert + 0.5;
    for (int r = 0; r < 3; ++r) {
        const double td = lo + (hi - lo) * (double)(wv + 1) / 5.0;
        const float tf = (float)td;
        float s11 = 0.f, s12 = 0.f, s22 = 0.f, dc = 0.f;
        for (int i4 = lane; i4 < 512; i4 += 64) {
            const float4 dd = ((const float4*)sd2)[i4];
            const float4 e1 = ((const float4*)sw1)[i4];
            const float4 e2 = ((const float4*)sw2)[i4];
            const float df[4] = {dd.x, dd.y, dd.z, dd.w};
            const float f1[4] = {e1.x, e1.y, e1.z, e1.w};
            const float f2[4] = {e2.x, e2.y, e2.z, e2.w};
#pragma unroll
            for (int e = 0; e < 4; ++e) {
                float den = df[e] - tf;
                float mag = fmaxf(fabsf(den), 1e-30f);
                den = (den < 0.f) ? -mag : mag;
                const float inv = __builtin_amdgcn_rcpf(den);
                s11 = fmaf(f1[e] * f1[e], inv, s11);
                s12 = fmaf(f1[e] * f2[e], inv, s12);
                s22 = fmaf(f2[e] * f2[e], inv, s22);
                if (df[e] < tf) dc += 1.f;
            }
        }
        s11 = wsumf(s11); s12 = wsumf(s12); s22 = wsumf(s22); dc = wsumf(dc);
        if (lane == 0)
            ish[wv] = inert((double)s11, (double)s12, (double)s22, (double)dc, cS);
        __syncthreads();
        double nlo = lo, nhi = hi;
        for (int i = 0; i < 4; ++i) {
            double ti = lo + (hi - lo) * (double)(i + 1) / 5.0;
            if (ish[i] >= 2048) { if (ti < nhi) nhi = ti; }
            else                { if (ti > nlo) nlo = ti; }
        }
        lo = nlo; hi = nhi;
        __syncthreads();
    }
    const double lmax = 0.5 * (lo + hi);
    const double rc = 10.0 * 2048.0 * 1.1920928955078125e-07;
    const double cut2 = rc * rc * lmax;

    // ---- Phase B: deterministic near-list compaction + far Taylor coeffs ----
    int flags = 0, lc = 0;
#pragma unroll
    for (int e = 0; e < 8; ++e)
        if (d2r[e] < THETA) { flags |= (1 << e); ++lc; }
    int sc = lc;
#pragma unroll
    for (int off = 1; off < 64; off <<= 1) {
        int y = __shfl_up(sc, off, 64);
        if (lane >= off) sc += y;
    }
    const int wtot = __shfl(sc, 63, 64);
    const int excl = sc - lc;
    if (lane == 0) ish[4 + wv] = wtot;
    __syncthreads();
    int base = excl;
    for (int w = 0; w < wv; ++w) base += ish[4 + w];
    int cnt = 0;
    for (int w = 0; w < 4; ++w) cnt += ish[4 + w];
    {
        int pos = base;
#pragma unroll
        for (int e = 0; e < 8; ++e) {
            if (flags & (1 << e)) {
                if (pos < NL_CAP) { nl0[pos] = d2r[e]; nl1[pos] = w1r[e]; nl2[pos] = w2r[e]; }
                ++pos;
            }
        }
    }
    const int cntPad = (cnt + 7) & ~7;
    if (tid == 0) {
        for (int i = cnt; i < cntPad && i < NL_CAP; ++i) {
            nl0[i] = 1e30f; nl1[i] = 0.f; nl2[i] = 0.f;
        }
        ish[8] = cnt; ish[10] = cntPad >> 2;
    }

    float cff[12];
#pragma unroll
    for (int c = 0; c < 12; ++c) cff[c] = 0.f;
#pragma unroll
    for (int e = 0; e < 8; ++e) {
        if (d2r[e] >= THETA) {
            float id = __builtin_amdgcn_rcpf(d2r[e]);
            float b1 = w1r[e], b2 = w2r[e];
            float x11 = b1 * b1, x12 = b1 * b2, x22 = b2 * b2;
            float f = id;
            cff[0] += x11 * f; cff[1]  += x12 * f; cff[2]  += x22 * f; f *= id;
            cff[3] += x11 * f; cff[4]  += x12 * f; cff[5]  += x22 * f; f *= id;
            cff[6] += x11 * f; cff[7]  += x12 * f; cff[8]  += x22 * f; f *= id;
            cff[9] += x11 * f; cff[10] += x12 * f; cff[11] += x22 * f;
        }
    }
#pragma unroll
    for (int c = 0; c < 12; ++c) cff[c] = wsumf(cff[c]);
    if (lane == 0) {
        double* dw = &dsh[16 + wv * 12];
#pragma unroll
        for (int c = 0; c < 12; ++c) dw[c] = (double)cff[c];
    }
    __syncthreads();
    if (tid < 12) {
        double s = 0;
        for (int w = 0; w < 4; ++w) s += dsh[16 + w * 12 + tid];
        dsh[96 + tid] = s;
    }
    __syncthreads();

    cnt = ish[8];
    const bool nearOK = (cnt <= NL_CAP - 8);
    const float4* l0 = nearOK ? (const float4*)nl0 : (const float4*)sd2;
    const float4* l1 = nearOK ? (const float4*)nl1 : (const float4*)sw1;
    const float4* l2 = nearOK ? (const float4*)nl2 : (const float4*)sw2;
    const int n4 = nearOK ? ish[10] : 512;
    const bool poly = nearOK;
    const double* pcoef = &dsh[96];

    double zg1, zg2, zg3;
    if (wv == 0) {
        int N = lane_evalN32((float)cut2, cut2, n4, l0, l1, l2, pcoef, poly, cS,
                             zg1, zg2, zg3);
        if (lane == 0) ish[9] = N;
    }
    __syncthreads();
    int m = ish[9];
    if (m < 0) m = 0;
    if (m > MAXM) m = MAXM;

    // ---- Phase C+D merged, per-wave, barrier-free ----
    for (int k = wv; k < m; k += 4) {
        double klo = 0.0, khi = cut2;
        for (int r = 0; r < 2; ++r) {
            const double w = khi - klo;
            const double td = klo + w * (double)(lane + 1) / 65.0;
            int N = lane_evalN32((float)td, td, n4, l0, l1, l2, pcoef, poly, cS,
                                 zg1, zg2, zg3);
            unsigned long long mask = __ballot(N >= k + 1);
            int j = (mask == 0ull) ? 64 : (__ffsll(mask) - 1);
            double nk = (j == 64) ? khi : (klo + w * (double)(j + 1) / 65.0);
            klo = klo + w * (double)j / 65.0;
            khi = nk;
        }
        const double lam = 0.5 * (klo + khi);
        double g11, g12, g22;
        lane_evalN32((float)lam, lam, n4, l0, l1, l2, pcoef, poly, cS, g11, g12, g22);
        const double m00 = 1.0 + g12, m01 = g11 + cS * g12;
        const double m10 = g22,       m11 = 1.0 + g12 + cS * g22;
        double y1, y2;
        if (m00 * m00 + m01 * m01 >= m10 * m10 + m11 * m11) { y1 = m01; y2 = -m00; }
        else                                                { y1 = m11; y2 = -m10; }
        double z1d = y2, z2d = y1 + cS * y2;
        const double zs = 1.0 / fmax(fmax(fabs(z1d), fabs(z2d)), 1e-300);
        const float z1 = (float)(z1d * zs), z2 = (float)(z2d * zs);
        const float lamf = (float)lam;

        // pass 1: wave-local norm over the full vector (32 elems/lane)
        float pn = 0.f;
#pragma unroll
        for (int c = 0; c < 8; ++c) {
            const int idx = c * 256 + lane * 4;
            const float4 d4 = *(const float4*)&sd2[idx];
            const float4 x4 = *(const float4*)&sw1[idx];
            const float4 y4 = *(const float4*)&sw2[idx];
            const float dd[4] = {d4.x, d4.y, d4.z, d4.w};
            const float xx[4] = {x4.x, x4.y, x4.z, x4.w};
            const float yy[4] = {y4.x, y4.y, y4.z, y4.w};
#pragma unroll
            for (int e = 0; e < 4; ++e) {
                float den = dd[e] - lamf;                  // Sterbenz-exact
                float mag = fmaxf(fabsf(den), 1e-12f);
                den = (den < 0.f) ? -mag : mag;
                const float vi = (xx[e] * z1 + yy[e] * z2) * __builtin_amdgcn_rcpf(den);
                pn = fmaf(vi, vi, pn);
            }
        }
        pn = wsumf(pn);
        const float inv = 1.0f / sqrtf(pn);

        // pass 2: recompute and write normalized eigenvector
#pragma unroll
        for (int c = 0; c < 8; ++c) {
            const int idx = c * 256 + lane * 4;
            const float4 d4 = *(const float4*)&sd2[idx];
            const float4 x4 = *(const float4*)&sw1[idx];
            const float4 y4 = *(const float4*)&sw2[idx];
            const float dd[4] = {d4.x, d4.y, d4.z, d4.w};
            const float xx[4] = {x4.x, x4.y, x4.z, x4.w};
            const float yy[4] = {y4.x, y4.y, y4.z, y4.w};
            float o0[4];
#pragma unroll
            for (int e = 0; e < 4; ++e) {
                float den = dd[e] - lamf;
                float mag = fmaxf(fabsf(den), 1e-12f);
                den = (den < 0.f) ? -mag : mag;
                o0[e] = (xx[e] * z1 + yy[e] * z2) * __builtin_amdgcn_rcpf(den) * inv;
            }
            *(float4*)&V[(size_t)k * 2048 + idx] = *(float4*)&o0[0];
        }
    }

    if (tid == 0) { hdr[0] = lmax; hdr[1] = cut2; hdr[2] = (double)m; hdr[3] = cS; }
    __builtin_amdgcn_s_setprio(0);
}

// ==================== fat kernel: block 0 = spec (private CU), rest = split-K GEMM ====

__global__ __launch_bounds__(256)
void fat_k(const u16* __restrict__ A, const u16* __restrict__ B,
           float* __restrict__ C0, float* __restrict__ C1,
           int Ndim, int Kdim, int ntiles, int nbx, int nsplit,
           const float* __restrict__ av, const float* __restrict__ pv,
           const float* __restrict__ qv, double* __restrict__ hdr,
           float* __restrict__ V)
{
    __shared__ __align__(16) unsigned char smem[SMEM_BYTES];
    const int bid = blockIdx.x;
    if (bid == 0) {
        spec256(smem, threadIdx.x, av, pv, qv, hdr, V);
        return;
    }
    if ((bid & 255) == 0) return;          // pad: keeps spec's CU private
    const int t = bid - 1 - (bid >> 8);    // tile index net of pads
    if (t >= ntiles * nsplit) return;
    const int ks = t / ntiles;
    const int tt = t - ks * ntiles;
    const int Klen = Kdim / nsplit;
    gemm_tile((u16*)smem, threadIdx.x, tt % nbx, tt / nbx,
              A + (size_t)ks * Klen, B + (size_t)ks * Klen,
              ks ? C1 : C0, Ndim, Kdim, Klen);
}

// ==================== wave-per-row fused series kernel (H == 2048) ====================

__global__ __launch_bounds__(256, 2)
void series_k(float* __restrict__ io, const float* __restrict__ io2, int addP,
              const float* __restrict__ hm,
              const float* __restrict__ qv, const float* __restrict__ pv,
              const float* __restrict__ av, const float* __restrict__ delta,
              const float* __restrict__ V, const double* __restrict__ hdr,
              int useTrunc)
{
    const int lane = threadIdx.x & 63;
    const int row = blockIdx.x * 4 + (threadIdx.x >> 6);
    const float d = delta[0];
    const int m = useTrunc ? (int)hdr[2] : 0;

    float q[32], p[32], a[32], t[32], o[32];
    float* iorow = io + (size_t)row * 2048;
    const float* io2row = io2 + (size_t)row * 2048;
#pragma unroll
    for (int cc = 0; cc < 8; ++cc) {
        const int j = cc * 256 + lane * 4;
        *(float4*)&q[cc * 4] = *(const float4*)&qv[j];
        *(float4*)&p[cc * 4] = *(const float4*)&pv[j];
        *(float4*)&a[cc * 4] = *(const float4*)&av[j];
        float4 u0 = *(const float4*)&iorow[j];
        if (addP) {
            const float4 u1 = *(const float4*)&io2row[j];
            u0.x += u1.x; u0.y += u1.y; u0.z += u1.z; u0.w += u1.w;
        }
        *(float4*)&t[cc * 4] = u0;
    }
#pragma unroll
    for (int e = 0; e < 32; ++e) o[e] = t[e];

    float cf = 1.f;
    for (int k = 1; k <= 13; ++k) {
        float s = 0.f;
#pragma unroll
        for (int e = 0; e < 32; ++e) s += t[e] * q[e];
#pragma unroll
        for (int msk = 32; msk; msk >>= 1) s += __shfl_xor(s, msk, 64);
        cf /= (float)(k + 1);
        const float ds = d * s;
#pragma unroll
        for (int e = 0; e < 32; ++e) { t[e] = d * a[e] * t[e] + ds * p[e]; o[e] += cf * t[e]; }
    }
#pragma unroll
    for (int e = 0; e < 32; ++e) o[e] *= d;

    for (int k = 0; k < m; ++k) {
        const float* vr = V + (size_t)k * 2048;
        float vk[32];
#pragma unroll
        for (int cc = 0; cc < 8; ++cc)
            *(float4*)&vk[cc * 4] = *(const float4*)&vr[cc * 256 + lane * 4];
        float s = 0.f;
#pragma unroll
        for (int e = 0; e < 32; ++e) s += o[e] * vk[e];
#pragma unroll
        for (int msk = 32; msk; msk >>= 1) s += __shfl_xor(s, msk, 64);
#pragma unroll
        for (int e = 0; e < 32; ++e) o[e] -= s * vk[e];
    }

    const float* hrow = hm + (size_t)row * 2048;
#pragma unroll
    for (int cc = 0; cc < 8; ++cc)
        *(float4*)&t[cc * 4] = *(const float4*)&hrow[cc * 256 + lane * 4];
#pragma unroll
    for (int e = 0; e < 32; ++e) o[e] += t[e];
    cf = 1.f;
    for (int k = 1; k <= 14; ++k) {
        float s = 0.f;
#pragma unroll
        for (int e = 0; e < 32; ++e) s += t[e] * q[e];
#pragma unroll
        for (int msk = 32; msk; msk >>= 1) s += __shfl_xor(s, msk, 64);
        cf /= (float)k;
        const float ds = d * s;
#pragma unroll
        for (int e = 0; e < 32; ++e) { t[e] = d * a[e] * t[e] + ds * p[e]; o[e] += cf * t[e]; }
    }
#pragma unroll
    for (int cc = 0; cc < 8; ++cc)
        *(float4*)&iorow[cc * 256 + lane * 4] = *(const float4*)&o[cc * 4];
}

// ==================== host orchestration ====================
// out = h expm(dA)^T + d*(x b^T) phi1(dA^T) (I - P_V);  P_V = truncated
// right-singular subspace of A per jnp.linalg.pinv rcond (exact identity).
// conv -> fat(spec private CU || split-K=2 quad-buffer GEMM) -> series.

extern "C" void kernel_launch(void* const* d_in, const int* in_sizes, int n_in,
                              void* d_out, int out_size, void* d_ws, size_t ws_size,
                              hipStream_t stream)
{
    const float* hmat  = (const float*)d_in[0];
    const float* xmat  = (const float*)d_in[1];
    const float* adiag = (const float*)d_in[2];
    const float* pvec  = (const float*)d_in[3];
    const float* qvec  = (const float*)d_in[4];
    const float* bmat  = (const float*)d_in[5];
    const float* delta = (const float*)d_in[6];
    float* out = (float*)d_out;

    const int H  = in_sizes[2];
    const int Bb = in_sizes[0] / H;
    const size_t SZ = (size_t)Bb * H;
    const size_t HH = (size_t)H * H;

    double* hdr = (double*)d_ws;
    float* V = (float*)(hdr + 8);
    u16* xb = (u16*)(V + (size_t)MAXM * H);
    u16* bb = xb + SZ;
    float* C1 = (float*)(bb + HH);

    const size_t needSpec  = 64 + (size_t)MAXM * H * sizeof(float);
    const size_t needFull  = needSpec + (SZ + HH) * sizeof(u16);
    const size_t needSplit = needFull + SZ * sizeof(float);
    const bool doTrunc = (H == 2048) && (ws_size >= needSpec);
    const bool doBf16  = (ws_size >= needFull) && (H % 128 == 0) && (Bb % 128 == 0);
    const bool doSplit = doBf16 && doTrunc && (ws_size >= needSplit);

    dim3 blk256(256);
    const int nbx = H / 128;
    const int ntiles = nbx * (Bb / 128);

    if (doBf16) {
        const long nmax = (long)(SZ > HH ? SZ : HH);
        const int cg = (int)((nmax / 4 + 255) / 256);
        conv_k<<<cg, blk256, 0, stream>>>(xmat, bmat, xb, bb, (long)SZ, (long)HH);
        if (doTrunc) {
            const int nsplit = doSplit ? 2 : 1;
            const int NT = ntiles * nsplit;
            const int grid = 1 + NT + (NT + 254) / 255;   // spec + tiles + pads
            fat_k<<<grid, blk256, 0, stream>>>(
                xb, bb, out, C1, H, H, ntiles, nbx, nsplit,
                adiag, pvec, qvec, hdr, V);
        } else {
            dim3 gg(nbx, Bb / 128);
            bgemm_k<<<gg, blk256, 0, stream>>>(xb, bb, out, H, H);
        }
    } else {
        if (doTrunc)
            fat_k<<<1, blk256, 0, stream>>>(nullptr, nullptr, out, nullptr,
                                            H, H, 0, 1, 1,
                                            adiag, pvec, qvec, hdr, V);
        dim3 gg(H / 64, Bb / 128);
        g_sgemm_k<<<gg, blk256, 0, stream>>>(xmat, bmat, out, Bb, H, H);
    }

    // fused series + projection (+ split-K partial sum), in-place on d_out
    series_k<<<Bb / 4, blk256, 0, stream>>>(out, doSplit ? C1 : out,
                                            doSplit ? 1 : 0,
                                            hmat, qvec, pvec, adiag, delta,
                                            V, hdr, doTrunc ? 1 : 0);
}

// Round 20
// 77.132 us; speedup vs baseline: 1.0368x; 1.0368x over previous
//
#include <hip/hip_runtime.h>

#define MAXM 16
#define NL_CAP 256
#define THETA 0.02f
#define SMEM_BYTES 32768

typedef unsigned short u16;
typedef u16 u16x8 __attribute__((ext_vector_type(8)));
typedef u16 u16x4 __attribute__((ext_vector_type(4)));
typedef __bf16 bf16x8 __attribute__((ext_vector_type(8)));
typedef float f32x4 __attribute__((ext_vector_type(4)));

// ==================== f32 -> bf16 (RNE) ====================

__device__ __forceinline__ u16 f2bf(float f) {
    unsigned u = __float_as_uint(f);
    return (u16)((u + 0x7fffu + ((u >> 16) & 1u)) >> 16);
}

__global__ __launch_bounds__(256)
void conv_k(const float* __restrict__ x, const float* __restrict__ b,
            u16* __restrict__ xb, u16* __restrict__ bb, long nx, long nb)
{
    long i = ((long)blockIdx.x * 256 + threadIdx.x) * 4;
    if (i < nx) {
        float4 v = *(const float4*)&x[i];
        u16x4 o = {f2bf(v.x), f2bf(v.y), f2bf(v.z), f2bf(v.w)};
        *(u16x4*)&xb[i] = o;
    }
    if (i < nb) {
        float4 v = *(const float4*)&b[i];
        u16x4 o = {f2bf(v.x), f2bf(v.y), f2bf(v.z), f2bf(v.w)};
        *(u16x4*)&bb[i] = o;
    }
}

// ==================== fast f64 reciprocal ====================

__device__ __forceinline__ double frcp(double den) {
    double r = (double)__builtin_amdgcn_rcpf((float)den);
    return fma(r, fma(-den, r, 1.0), r);
}

// ==================== bf16 MFMA GEMM tile: dbuf + counted vmcnt + XOR swizzle ====
// [row][32]-u16 LDS has 64B row stride -> quarter-wave ds_read_b128 hits
// 2 banks (8-way conflict, 2.94x). Fix per rule #21 (gload_lds writes
// linearly): pre-swizzle the GLOBAL source chunk (chunk' = chunk^(row&3),
// 16B units) and XOR the read offset the same way -> lanes spread over
// 4 banks (1.58x). Self-inverse, bijective per row.

__device__ __forceinline__ void gload_lds16(const void* g, void* l) {
    __builtin_amdgcn_global_load_lds(
        (const __attribute__((address_space(1))) unsigned int*)g,
        (__attribute__((address_space(3))) unsigned int*)l, 16, 0, 0);
}

__device__ __forceinline__ void gemm_tile(u16* Al, u16* Bl, int tid, int bx, int by,
                                          const u16* __restrict__ A,
                                          const u16* __restrict__ B,
                                          float* __restrict__ C,
                                          int Ndim, int Kstride, int Klen)
{
    const int bm = by * 128, bn = bx * 128;
    const int wv = tid >> 6, ln = tid & 63;
    const int wr = (wv >> 1) * 64, wc = (wv & 1) * 64;
    const int fr = ln & 15, fk = (ln >> 4) * 8;
    const int fk2 = fk ^ ((fr & 3) << 3);     // read-side XOR (elements)

    // staging: thread stages LDS chunk c = tid (rows 0..63) and c+256
    // (rows 64..127); row = tid>>2. Source col chunk = (tid&3) ^ (row&3).
    const int r0 = tid >> 2;
    const int c0 = ((tid & 3) ^ (r0 & 3)) * 8;    // pre-swizzled source col
    const u16* Ap0 = A + (size_t)(bm + r0) * Kstride + c0;
    const u16* Ap1 = Ap0 + (size_t)64 * Kstride;  // (r0+64)&3 == r0&3
    const u16* Bp0 = B + (size_t)(bn + r0) * Kstride + c0;
    const u16* Bp1 = Bp0 + (size_t)64 * Kstride;

    f32x4 acc[4][4];
#pragma unroll
    for (int m = 0; m < 4; ++m)
#pragma unroll
        for (int n = 0; n < 4; ++n) acc[m][n] = (f32x4)0.f;

    // prologue: stage K-tile 0 into buffer 0
    {
        u16* a0 = Al + wv * 512;
        u16* a1 = Al + 2048 + wv * 512;
        u16* b0 = Bl + wv * 512;
        u16* b1 = Bl + 2048 + wv * 512;
        gload_lds16(Ap0, a0);
        gload_lds16(Ap1, a1);
        gload_lds16(Bp0, b0);
        gload_lds16(Bp1, b1);
    }

    int cur = 0;
    for (int kk = 0; kk < Klen; kk += 32) {
        const bool hasNext = (kk + 32 < Klen);
        if (hasNext) {
            const int nb = (cur ^ 1) * 4096;
            u16* a0 = Al + nb + wv * 512;
            u16* a1 = Al + nb + 2048 + wv * 512;
            u16* b0 = Bl + nb + wv * 512;
            u16* b1 = Bl + nb + 2048 + wv * 512;
            gload_lds16(Ap0 + kk + 32, a0);
            gload_lds16(Ap1 + kk + 32, a1);
            gload_lds16(Bp0 + kk + 32, b0);
            gload_lds16(Bp1 + kk + 32, b1);
            asm volatile("s_waitcnt vmcnt(4)" ::: "memory");  // cur landed; next in flight
        } else {
            asm volatile("s_waitcnt vmcnt(0)" ::: "memory");
        }
        __builtin_amdgcn_sched_barrier(0);
        __builtin_amdgcn_s_barrier();          // all waves' cur-loads landed

        const int cb = cur * 4096;
        u16x8 af[4], bf[4];
#pragma unroll
        for (int m = 0; m < 4; ++m)
            af[m] = *(const u16x8*)&Al[cb + (wr + m * 16 + fr) * 32 + fk2];
#pragma unroll
        for (int n = 0; n < 4; ++n)
            bf[n] = *(const u16x8*)&Bl[cb + (wc + n * 16 + fr) * 32 + fk2];
#pragma unroll
        for (int m = 0; m < 4; ++m)
#pragma unroll
            for (int n = 0; n < 4; ++n)
                acc[m][n] = __builtin_amdgcn_mfma_f32_16x16x32_bf16(
                    __builtin_bit_cast(bf16x8, af[m]),
                    __builtin_bit_cast(bf16x8, bf[n]), acc[m][n], 0, 0, 0);

        __builtin_amdgcn_sched_barrier(0);     // keep ds_reads above barrier2
        __builtin_amdgcn_s_barrier();          // reads done -> next iter may overwrite
        cur ^= 1;
    }

    const int crow = (ln >> 4) * 4;
#pragma unroll
    for (int m = 0; m < 4; ++m)
#pragma unroll
        for (int n = 0; n < 4; ++n) {
            const size_t base = (size_t)(bm + wr + m * 16 + crow) * Ndim
                              + bn + wc + n * 16 + fr;
#pragma unroll
            for (int j = 0; j < 4; ++j)
                C[base + (size_t)j * Ndim] = acc[m][n][j];
        }
}

__global__ __launch_bounds__(256)
void bgemm_k(const u16* __restrict__ A, const u16* __restrict__ B,
             float* __restrict__ C, int Ndim, int Kdim)
{
    __shared__ __align__(16) unsigned char smem[SMEM_BYTES];
    gemm_tile((u16*)smem, (u16*)smem + 8192, threadIdx.x,
              blockIdx.x, blockIdx.y, A, B, C, Ndim, Kdim, Kdim);
}

// ==================== f32 fallback GEMM (ws too small) ====================

__global__ __launch_bounds__(256)
void g_sgemm_k(const float* __restrict__ A, const float* __restrict__ B,
               float* __restrict__ C, int Mdim, int Ndim, int Kdim)
{
    __shared__ __align__(16) float As[16][132];
    __shared__ __align__(16) float Bs[16][68];
    const int tid = threadIdx.x;
    const int tx = tid & 15, ty = tid >> 4;
    const int bn = blockIdx.x * 64, bm = blockIdx.y * 128;
    const int lrA = tid >> 1, lcA = (tid & 1) << 3;
    const int lrB = tid >> 2, lcB = (tid & 3) << 2;
    const float* Aptr = A + (size_t)(bm + lrA) * Kdim + lcA;
    const float* Bptr = B + (size_t)(bn + lrB) * Kdim + lcB;
    float4 a0 = *(const float4*)(Aptr);
    float4 a1 = *(const float4*)(Aptr + 4);
    float4 b0 = *(const float4*)(Bptr);
    float acc[8][4];
#pragma unroll
    for (int i = 0; i < 8; ++i)
#pragma unroll
        for (int j = 0; j < 4; ++j) acc[i][j] = 0.f;
    for (int kk = 0; kk < Kdim; kk += 16) {
        __syncthreads();
        As[lcA + 0][lrA] = a0.x; As[lcA + 1][lrA] = a0.y;
        As[lcA + 2][lrA] = a0.z; As[lcA + 3][lrA] = a0.w;
        As[lcA + 4][lrA] = a1.x; As[lcA + 5][lrA] = a1.y;
        As[lcA + 6][lrA] = a1.z; As[lcA + 7][lrA] = a1.w;
        Bs[lcB + 0][lrB] = b0.x; Bs[lcB + 1][lrB] = b0.y;
        Bs[lcB + 2][lrB] = b0.z; Bs[lcB + 3][lrB] = b0.w;
        __syncthreads();
        if (kk + 16 < Kdim) {
            a0 = *(const float4*)(Aptr + kk + 16);
            a1 = *(const float4*)(Aptr + kk + 20);
            b0 = *(const float4*)(Bptr + kk + 16);
        }
#pragma unroll
        for (int k = 0; k < 16; ++k) {
            const float4 av0 = *(const float4*)&As[k][ty * 8];
            const float4 av1 = *(const float4*)&As[k][ty * 8 + 4];
            const float4 bv  = *(const float4*)&Bs[k][tx * 4];
            const float avf[8] = {av0.x, av0.y, av0.z, av0.w, av1.x, av1.y, av1.z, av1.w};
            const float bvf[4] = {bv.x, bv.y, bv.z, bv.w};
#pragma unroll
            for (int i = 0; i < 8; ++i)
#pragma unroll
                for (int j = 0; j < 4; ++j) acc[i][j] += avf[i] * bvf[j];
        }
    }
#pragma unroll
    for (int i = 0; i < 8; ++i) {
        const int r = bm + ty * 8 + i;
        float4 v = {acc[i][0], acc[i][1], acc[i][2], acc[i][3]};
        *(float4*)&C[(size_t)r * Ndim + bn + tx * 4] = v;
    }
}

// ==================== spectral solve (device fn, 256 thr, H == 2048) ====================
// R17 structure (VGPR-lean: block-coop Phase D) + Weyl bracket Phase A.

__device__ __forceinline__ double wsum(double x) {
#pragma unroll
    for (int m = 32; m; m >>= 1) x += __shfl_xor(x, m, 64);
    return x;
}
__device__ __forceinline__ float wsumf(float x) {
#pragma unroll
    for (int m = 32; m; m >>= 1) x += __shfl_xor(x, m, 64);
    return x;
}

__device__ __forceinline__ int inert(double s11, double s12, double s22,
                                     double dc, double cS)
{
    double b00 = cS - s11, b01 = -1.0 - s12, b11 = -s22;   // -S^{-1} - G
    double det = b00 * b11 - b01 * b01, tr = b00 + b11;
    int neg = (det > 0.0) ? ((tr < 0.0) ? 2 : 0) : 1;
    return (int)(dc + 0.5) + neg - 1;
}

__device__ __forceinline__ int lane_evalN32(float tf, double td, int n4,
    const float4* l0, const float4* l1, const float4* l2,
    const double* pc, bool poly, double cS,
    double& g11o, double& g12o, double& g22o)
{
    float s11 = 0.f, s12 = 0.f, s22 = 0.f, dc = 0.f;
#pragma unroll 4
    for (int i = 0; i < n4; ++i) {
        const float4 d4 = l0[i], x4 = l1[i], y4 = l2[i];
        const float dd[4] = {d4.x, d4.y, d4.z, d4.w};
        const float xx[4] = {x4.x, x4.y, x4.z, x4.w};
        const float yy[4] = {y4.x, y4.y, y4.z, y4.w};
#pragma unroll
        for (int e = 0; e < 4; ++e) {
            float den = dd[e] - tf;
            float mag = fmaxf(fabsf(den), 1e-30f);
            den = (den < 0.f) ? -mag : mag;
            const float inv = __builtin_amdgcn_rcpf(den);
            s11 = fmaf(xx[e] * xx[e], inv, s11);
            s12 = fmaf(xx[e] * yy[e], inv, s12);
            s22 = fmaf(yy[e] * yy[e], inv, s22);
            if (dd[e] < tf) dc += 1.f;
        }
    }
    double S11 = (double)s11, S12 = (double)s12, S22 = (double)s22;
    if (poly) {
        S11 += pc[0] + td * (pc[3] + td * (pc[6] + td * pc[9]));
        S12 += pc[1] + td * (pc[4] + td * (pc[7] + td * pc[10]));
        S22 += pc[2] + td * (pc[5] + td * (pc[8] + td * pc[11]));
    }
    g11o = S11; g12o = S12; g22o = S22;
    return inert(S11, S12, S22, (double)dc, cS);
}

__device__ void spec256(unsigned char* smem, int tid,
                        const float* __restrict__ av, const float* __restrict__ pv,
                        const float* __restrict__ qv, double* __restrict__ hdr,
                        float* __restrict__ V)
{
    __builtin_amdgcn_s_setprio(1);

    float* sd2 = (float*)smem;          // 2048
    float* sw1 = sd2 + 2048;
    float* sw2 = sw1 + 2048;
    float* nl0 = sw2 + 2048;            // NL_CAP each
    float* nl1 = nl0 + NL_CAP;
    float* nl2 = nl1 + NL_CAP;
    double* dsh = (double*)(nl2 + NL_CAP);   // 192 doubles
    int* ish = (int*)(dsh + 192);            // 16 ints

    const int lane = tid & 63, wv = tid >> 6;
    const int j0 = tid * 8;

    float d2r[8], w1r[8], w2r[8];
    double cS = 0, n1 = 0, n2 = 0, mx = 0;
#pragma unroll
    for (int h = 0; h < 2; ++h) {
        float4 aa = *(const float4*)&av[j0 + h * 4];
        float4 pp = *(const float4*)&pv[j0 + h * 4];
        float4 qq = *(const float4*)&qv[j0 + h * 4];
        const float a4[4] = {aa.x, aa.y, aa.z, aa.w};
        const float p4[4] = {pp.x, pp.y, pp.z, pp.w};
        const float q4[4] = {qq.x, qq.y, qq.z, qq.w};
#pragma unroll
        for (int e = 0; e < 4; ++e) {
            const int ix = h * 4 + e;
            d2r[ix] = a4[e] * a4[e];
            w1r[ix] = a4[e] * p4[e];
            w2r[ix] = q4[e];
            sd2[j0 + ix] = d2r[ix]; sw1[j0 + ix] = w1r[ix]; sw2[j0 + ix] = w2r[ix];
            cS += (double)p4[e] * p4[e];
            n1 += (double)w1r[ix] * w1r[ix];
            n2 += (double)w2r[ix] * w2r[ix];
            mx = fmax(mx, (double)d2r[ix]);
        }
    }
    cS = wsum(cS); n1 = wsum(n1); n2 = wsum(n2);
#pragma unroll
    for (int m_ = 32; m_; m_ >>= 1) mx = fmax(mx, __shfl_xor(mx, m_, 64));
    __syncthreads();
    if (lane == 0) { dsh[wv] = cS; dsh[4 + wv] = n1; dsh[8 + wv] = n2; dsh[12 + wv] = mx; }
    __syncthreads();
    cS = 0; n1 = 0; n2 = 0; mx = 0;
    for (int w = 0; w < 4; ++w) {
        cS += dsh[w]; n1 += dsh[4 + w]; n2 += dsh[8 + w];
        mx = fmax(mx, dsh[12 + w]);
    }
    __syncthreads();

    // ---- Phase A: lambda_max 5-section x 3 rounds on Weyl bracket ----
    const double pert = 2.0 * sqrt(n1 * n2) + cS * n2;
    double lo = fmax(0.0, mx - pert);
    double hi = mx + pert + 0.5;
    for (int r = 0; r < 3; ++r) {
        const double td = lo + (hi - lo) * (double)(wv + 1) / 5.0;
        const float tf = (float)td;
        float s11 = 0.f, s12 = 0.f, s22 = 0.f, dc = 0.f;
        for (int i4 = lane; i4 < 512; i4 += 64) {
            const float4 dd = ((const float4*)sd2)[i4];
            const float4 e1 = ((const float4*)sw1)[i4];
            const float4 e2 = ((const float4*)sw2)[i4];
            const float df[4] = {dd.x, dd.y, dd.z, dd.w};
            const float f1[4] = {e1.x, e1.y, e1.z, e1.w};
            const float f2[4] = {e2.x, e2.y, e2.z, e2.w};
#pragma unroll
            for (int e = 0; e < 4; ++e) {
                float den = df[e] - tf;
                float mag = fmaxf(fabsf(den), 1e-30f);
                den = (den < 0.f) ? -mag : mag;
                const float inv = __builtin_amdgcn_rcpf(den);
                s11 = fmaf(f1[e] * f1[e], inv, s11);
                s12 = fmaf(f1[e] * f2[e], inv, s12);
                s22 = fmaf(f2[e] * f2[e], inv, s22);
                if (df[e] < tf) dc += 1.f;
            }
        }
        s11 = wsumf(s11); s12 = wsumf(s12); s22 = wsumf(s22); dc = wsumf(dc);
        if (lane == 0)
            ish[wv] = inert((double)s11, (double)s12, (double)s22, (double)dc, cS);
        __syncthreads();
        double nlo = lo, nhi = hi;
        for (int i = 0; i < 4; ++i) {
            double ti = lo + (hi - lo) * (double)(i + 1) / 5.0;
            if (ish[i] >= 2048) { if (ti < nhi) nhi = ti; }
            else                { if (ti > nlo) nlo = ti; }
        }
        lo = nlo; hi = nhi;
        __syncthreads();
    }
    const double lmax = 0.5 * (lo + hi);
    const double rc = 10.0 * 2048.0 * 1.1920928955078125e-07;
    const double cut2 = rc * rc * lmax;

    // ---- Phase B: deterministic near-list compaction + far Taylor coeffs ----
    int flags = 0, lc = 0;
#pragma unroll
    for (int e = 0; e < 8; ++e)
        if (d2r[e] < THETA) { flags |= (1 << e); ++lc; }
    int sc = lc;
#pragma unroll
    for (int off = 1; off < 64; off <<= 1) {
        int y = __shfl_up(sc, off, 64);
        if (lane >= off) sc += y;
    }
    const int wtot = __shfl(sc, 63, 64);
    const int excl = sc - lc;
    if (lane == 0) ish[4 + wv] = wtot;
    __syncthreads();
    int base = excl;
    for (int w = 0; w < wv; ++w) base += ish[4 + w];
    int cnt = 0;
    for (int w = 0; w < 4; ++w) cnt += ish[4 + w];
    {
        int pos = base;
#pragma unroll
        for (int e = 0; e < 8; ++e) {
            if (flags & (1 << e)) {
                if (pos < NL_CAP) { nl0[pos] = d2r[e]; nl1[pos] = w1r[e]; nl2[pos] = w2r[e]; }
                ++pos;
            }
        }
    }
    const int cntPad = (cnt + 7) & ~7;
    if (tid == 0) {
        for (int i = cnt; i < cntPad && i < NL_CAP; ++i) {
            nl0[i] = 1e30f; nl1[i] = 0.f; nl2[i] = 0.f;
        }
        ish[8] = cnt; ish[10] = cntPad >> 2;
    }

    float cff[12];
#pragma unroll
    for (int c = 0; c < 12; ++c) cff[c] = 0.f;
#pragma unroll
    for (int e = 0; e < 8; ++e) {
        if (d2r[e] >= THETA) {
            float id = __builtin_amdgcn_rcpf(d2r[e]);
            float b1 = w1r[e], b2 = w2r[e];
            float x11 = b1 * b1, x12 = b1 * b2, x22 = b2 * b2;
            float f = id;
            cff[0] += x11 * f; cff[1]  += x12 * f; cff[2]  += x22 * f; f *= id;
            cff[3] += x11 * f; cff[4]  += x12 * f; cff[5]  += x22 * f; f *= id;
            cff[6] += x11 * f; cff[7]  += x12 * f; cff[8]  += x22 * f; f *= id;
            cff[9] += x11 * f; cff[10] += x12 * f; cff[11] += x22 * f;
        }
    }
#pragma unroll
    for (int c = 0; c < 12; ++c) cff[c] = wsumf(cff[c]);
    if (lane == 0) {
        double* dw = &dsh[16 + wv * 12];
#pragma unroll
        for (int c = 0; c < 12; ++c) dw[c] = (double)cff[c];
    }
    __syncthreads();
    if (tid < 12) {
        double s = 0;
        for (int w = 0; w < 4; ++w) s += dsh[16 + w * 12 + tid];
        dsh[96 + tid] = s;
    }
    __syncthreads();

    cnt = ish[8];
    const bool nearOK = (cnt <= NL_CAP - 8);
    const float4* l0 = nearOK ? (const float4*)nl0 : (const float4*)sd2;
    const float4* l1 = nearOK ? (const float4*)nl1 : (const float4*)sw1;
    const float4* l2 = nearOK ? (const float4*)nl2 : (const float4*)sw2;
    const int n4 = nearOK ? ish[10] : 512;
    const bool poly = nearOK;
    const double* pcoef = &dsh[96];

    double zg1, zg2, zg3;
    if (wv == 0) {
        int N = lane_evalN32((float)cut2, cut2, n4, l0, l1, l2, pcoef, poly, cS,
                             zg1, zg2, zg3);
        if (lane == 0) ish[9] = N;
    }
    __syncthreads();
    int m = ish[9];
    if (m < 0) m = 0;
    if (m > MAXM) m = MAXM;

    // ---- Phase C: per-lane 65-section (2 rounds + final), f32 evals ----
    for (int k = wv; k < m; k += 4) {
        double klo = 0.0, khi = cut2;
        for (int r = 0; r < 2; ++r) {
            const double w = khi - klo;
            const double td = klo + w * (double)(lane + 1) / 65.0;
            int N = lane_evalN32((float)td, td, n4, l0, l1, l2, pcoef, poly, cS,
                                 zg1, zg2, zg3);
            unsigned long long mask = __ballot(N >= k + 1);
            int j = (mask == 0ull) ? 64 : (__ffsll(mask) - 1);
            double nk = (j == 64) ? khi : (klo + w * (double)(j + 1) / 65.0);
            klo = klo + w * (double)j / 65.0;
            khi = nk;
        }
        const double lam = 0.5 * (klo + khi);
        double g11, g12, g22;
        lane_evalN32((float)lam, lam, n4, l0, l1, l2, pcoef, poly, cS, g11, g12, g22);
        const double m00 = 1.0 + g12, m01 = g11 + cS * g12;
        const double m10 = g22,       m11 = 1.0 + g12 + cS * g22;
        double y1, y2;
        if (m00 * m00 + m01 * m01 >= m10 * m10 + m11 * m11) { y1 = m01; y2 = -m00; }
        else                                                { y1 = m11; y2 = -m10; }
        double z1 = y2, z2 = y1 + cS * y2;
        const double zs = 1.0 / fmax(fmax(fabs(z1), fabs(z2)), 1e-300);
        if (lane == 0) {
            dsh[112 + 3 * k]     = lam;
            dsh[112 + 3 * k + 1] = z1 * zs;
            dsh[112 + 3 * k + 2] = z2 * zs;
        }
    }
    __syncthreads();

    // ---- Phase D: block-cooperative eigenvectors; f32 math, f64 subtract ----
    for (int k = 0; k < m; ++k) {
        const double lam = dsh[112 + 3 * k];
        const float z1 = (float)dsh[112 + 3 * k + 1];
        const float z2 = (float)dsh[112 + 3 * k + 2];
        float vr[8];
        float pn = 0.f;
#pragma unroll
        for (int e = 0; e < 8; ++e) {
            const double dend = (double)d2r[e] - lam;   // cancellation-safe
            float den = (float)dend;
            float mag = fmaxf(fabsf(den), 1e-12f);
            den = (den < 0.f) ? -mag : mag;
            const float vi = (w1r[e] * z1 + w2r[e] * z2) * __builtin_amdgcn_rcpf(den);
            pn = fmaf(vi, vi, pn);
            vr[e] = vi;
        }
        pn = wsumf(pn);
        if (lane == 0) dsh[160 + wv] = (double)pn;
        __syncthreads();
        double tot = 0;
        for (int w = 0; w < 4; ++w) tot += dsh[160 + w];
        const float inv = (float)(1.0 / sqrt(tot));
        float o0[8];
#pragma unroll
        for (int e = 0; e < 8; ++e) o0[e] = vr[e] * inv;
        *(float4*)&V[(size_t)k * 2048 + j0]     = *(float4*)&o0[0];
        *(float4*)&V[(size_t)k * 2048 + j0 + 4] = *(float4*)&o0[4];
        __syncthreads();
    }

    if (tid == 0) { hdr[0] = lmax; hdr[1] = cut2; hdr[2] = (double)m; hdr[3] = cS; }
    __builtin_amdgcn_s_setprio(0);
}

// ==================== fat kernel: block 0 = spec (private CU), rest = split-K GEMM ====

__global__ __launch_bounds__(256)
void fat_k(const u16* __restrict__ A, const u16* __restrict__ B,
           float* __restrict__ C0, float* __restrict__ C1,
           int Ndim, int Kdim, int ntiles, int nbx, int nsplit,
           const float* __restrict__ av, const float* __restrict__ pv,
           const float* __restrict__ qv, double* __restrict__ hdr,
           float* __restrict__ V)
{
    __shared__ __align__(16) unsigned char smem[SMEM_BYTES];
    const int bid = blockIdx.x;
    if (bid == 0) {
        spec256(smem, threadIdx.x, av, pv, qv, hdr, V);
        return;
    }
    if ((bid & 255) == 0) return;          // pad: keeps spec's CU private
    const int t = bid - 1 - (bid >> 8);    // tile index net of pads
    if (t >= ntiles * nsplit) return;
    const int ks = t / ntiles;
    const int tt = t - ks * ntiles;
    const int Klen = Kdim / nsplit;
    gemm_tile((u16*)smem, (u16*)smem + 8192, threadIdx.x,
              tt % nbx, tt / nbx,
              A + (size_t)ks * Klen, B + (size_t)ks * Klen,
              ks ? C1 : C0, Ndim, Kdim, Klen);
}

// ==================== wave-per-row fused series kernel (H == 2048) ====================

__global__ __launch_bounds__(256, 2)
void series_k(float* __restrict__ io, const float* __restrict__ io2, int addP,
              const float* __restrict__ hm,
              const float* __restrict__ qv, const float* __restrict__ pv,
              const float* __restrict__ av, const float* __restrict__ delta,
              const float* __restrict__ V, const double* __restrict__ hdr,
              int useTrunc)
{
    const int lane = threadIdx.x & 63;
    const int row = blockIdx.x * 4 + (threadIdx.x >> 6);
    const float d = delta[0];
    const int m = useTrunc ? (int)hdr[2] : 0;

    float q[32], p[32], a[32], t[32], o[32];
    float* iorow = io + (size_t)row * 2048;
    const float* io2row = io2 + (size_t)row * 2048;
#pragma unroll
    for (int cc = 0; cc < 8; ++cc) {
        const int j = cc * 256 + lane * 4;
        *(float4*)&q[cc * 4] = *(const float4*)&qv[j];
        *(float4*)&p[cc * 4] = *(const float4*)&pv[j];
        *(float4*)&a[cc * 4] = *(const float4*)&av[j];
        float4 u0 = *(const float4*)&iorow[j];
        if (addP) {
            const float4 u1 = *(const float4*)&io2row[j];
            u0.x += u1.x; u0.y += u1.y; u0.z += u1.z; u0.w += u1.w;
        }
        *(float4*)&t[cc * 4] = u0;
    }
#pragma unroll
    for (int e = 0; e < 32; ++e) o[e] = t[e];

    float cf = 1.f;
    for (int k = 1; k <= 13; ++k) {
        float s = 0.f;
#pragma unroll
        for (int e = 0; e < 32; ++e) s += t[e] * q[e];
#pragma unroll
        for (int msk = 32; msk; msk >>= 1) s += __shfl_xor(s, msk, 64);
        cf /= (float)(k + 1);
        const float ds = d * s;
#pragma unroll
        for (int e = 0; e < 32; ++e) { t[e] = d * a[e] * t[e] + ds * p[e]; o[e] += cf * t[e]; }
    }
#pragma unroll
    for (int e = 0; e < 32; ++e) o[e] *= d;

    for (int k = 0; k < m; ++k) {
        const float* vr = V + (size_t)k * 2048;
        float vk[32];
#pragma unroll
        for (int cc = 0; cc < 8; ++cc)
            *(float4*)&vk[cc * 4] = *(const float4*)&vr[cc * 256 + lane * 4];
        float s = 0.f;
#pragma unroll
        for (int e = 0; e < 32; ++e) s += o[e] * vk[e];
#pragma unroll
        for (int msk = 32; msk; msk >>= 1) s += __shfl_xor(s, msk, 64);
#pragma unroll
        for (int e = 0; e < 32; ++e) o[e] -= s * vk[e];
    }

    const float* hrow = hm + (size_t)row * 2048;
#pragma unroll
    for (int cc = 0; cc < 8; ++cc)
        *(float4*)&t[cc * 4] = *(const float4*)&hrow[cc * 256 + lane * 4];
#pragma unroll
    for (int e = 0; e < 32; ++e) o[e] += t[e];
    cf = 1.f;
    for (int k = 1; k <= 14; ++k) {
        float s = 0.f;
#pragma unroll
        for (int e = 0; e < 32; ++e) s += t[e] * q[e];
#pragma unroll
        for (int msk = 32; msk; msk >>= 1) s += __shfl_xor(s, msk, 64);
        cf /= (float)k;
        const float ds = d * s;
#pragma unroll
        for (int e = 0; e < 32; ++e) { t[e] = d * a[e] * t[e] + ds * p[e]; o[e] += cf * t[e]; }
    }
#pragma unroll
    for (int cc = 0; cc < 8; ++cc)
        *(float4*)&iorow[cc * 256 + lane * 4] = *(const float4*)&o[cc * 4];
}

// ==================== host orchestration ====================
// out = h expm(dA)^T + d*(x b^T) phi1(dA^T) (I - P_V);  P_V = truncated
// right-singular subspace of A per jnp.linalg.pinv rcond (exact identity).
// conv -> fat(spec private CU || split-K=2 swizzled-dbuf GEMM) -> series.

extern "C" void kernel_launch(void* const* d_in, const int* in_sizes, int n_in,
                              void* d_out, int out_size, void* d_ws, size_t ws_size,
                              hipStream_t stream)
{
    const float* hmat  = (const float*)d_in[0];
    const float* xmat  = (const float*)d_in[1];
    const float* adiag = (const float*)d_in[2];
    const float* pvec  = (const float*)d_in[3];
    const float* qvec  = (const float*)d_in[4];
    const float* bmat  = (const float*)d_in[5];
    const float* delta = (const float*)d_in[6];
    float* out = (float*)d_out;

    const int H  = in_sizes[2];
    const int Bb = in_sizes[0] / H;
    const size_t SZ = (size_t)Bb * H;
    const size_t HH = (size_t)H * H;

    double* hdr = (double*)d_ws;
    float* V = (float*)(hdr + 8);
    u16* xb = (u16*)(V + (size_t)MAXM * H);
    u16* bb = xb + SZ;
    float* C1 = (float*)(bb + HH);

    const size_t needSpec  = 64 + (size_t)MAXM * H * sizeof(float);
    const size_t needFull  = needSpec + (SZ + HH) * sizeof(u16);
    const size_t needSplit = needFull + SZ * sizeof(float);
    const bool doTrunc = (H == 2048) && (ws_size >= needSpec);
    const bool doBf16  = (ws_size >= needFull) && (H % 128 == 0) && (Bb % 128 == 0);
    const bool doSplit = doBf16 && doTrunc && (ws_size >= needSplit);

    dim3 blk256(256);
    const int nbx = H / 128;
    const int ntiles = nbx * (Bb / 128);

    if (doBf16) {
        const long nmax = (long)(SZ > HH ? SZ : HH);
        const int cg = (int)((nmax / 4 + 255) / 256);
        conv_k<<<cg, blk256, 0, stream>>>(xmat, bmat, xb, bb, (long)SZ, (long)HH);
        if (doTrunc) {
            const int nsplit = doSplit ? 2 : 1;
            const int NT = ntiles * nsplit;
            const int grid = 1 + NT + (NT + 254) / 255;   // spec + tiles + pads
            fat_k<<<grid, blk256, 0, stream>>>(
                xb, bb, out, C1, H, H, ntiles, nbx, nsplit,
                adiag, pvec, qvec, hdr, V);
        } else {
            dim3 gg(nbx, Bb / 128);
            bgemm_k<<<gg, blk256, 0, stream>>>(xb, bb, out, H, H);
        }
    } else {
        if (doTrunc)
            fat_k<<<1, blk256, 0, stream>>>(nullptr, nullptr, out, nullptr,
                                            H, H, 0, 1, 1,
                                            adiag, pvec, qvec, hdr, V);
        dim3 gg(H / 64, Bb / 128);
        g_sgemm_k<<<gg, blk256, 0, stream>>>(xmat, bmat, out, Bb, H, H);
    }

    // fused series + projection (+ split-K partial sum), in-place on d_out
    series_k<<<Bb / 4, blk256, 0, stream>>>(out, doSplit ? C1 : out,
                                            doSplit ? 1 : 0,
                                            hmat, qvec, pvec, adiag, delta,
                                            V, hdr, doTrunc ? 1 : 0);
}